// Round 8
// baseline (1979.136 us; speedup 1.0000x reference)
//
#include <hip/hip_runtime.h>
#include <cmath>

#define HID 51
#define BATCH 256
#define BLK 768       // 3 layer-sections x 256 (12 waves)
#define OUT_TID 716   // layer-2 section, wave 11, lane 12 (unit 51 slot = idle)

typedef _Float16 half2_t __attribute__((ext_vector_type(2)));

// One block per batch element. tid = layer*256 + unit*4 + gt (unit<51 valid).
// Each gate thread: wA = Wih row (vs h_{layer-1}), wB = Whh row (vs h_layer),
// packed fp16 (26 half2 VGPRs each). Layer0: wA = Whh1 row, wx = Wih1, no wB.
// h broadcast WITHOUT the LDS pipe: each lane loads ONE h pair (ds_read_b32,
// lanes 0..31 = row selA pairs, lanes 32..63 = row selB pairs), then
// 26 x { v_readlane -> sgpr ; v_dot2_f32_f16 } per row. 1 LDS instr per wave
// per tick instead of 14 ds_read_b128 (the r5/r6 LDS-issue bottleneck).
// Double-buffered h (read hb[tau&1], write hb[tau&1^1]) -> ONE barrier/tick.
// Gate quad gathered into gt==0 lane via 3 ds_swizzle; cell update in-wave.
// Output thread (OUT_TID, layer-2 wave): wA=0, wB=Wl, t_off=3 -> rides the
// normal path; obuf ring flushed 64-wide by wave 3 at (tau%64)==3 (all slots
// it reads were written before the previous barrier).

__device__ __forceinline__ float fsig(float v) {
    return __builtin_amdgcn_rcpf(1.f + __expf(-v));
}
__device__ __forceinline__ float ftanh(float v) {
    const float e = __expf(2.f * v);                 // inf-safe
    return fmaf(-2.f, __builtin_amdgcn_rcpf(e + 1.f), 1.f);
}
__device__ __forceinline__ half2_t h2bits(int b) {
    union { int i; half2_t h; } u; u.i = b; return u.h;
}

__global__ __launch_bounds__(BLK, 3)
void lstm3_kernel(const float* __restrict__ x,
                  const float* __restrict__ Wih1, const float* __restrict__ Whh1,
                  const float* __restrict__ bih1, const float* __restrict__ bhh1,
                  const float* __restrict__ Wih,  const float* __restrict__ Whh,
                  const float* __restrict__ bih,  const float* __restrict__ bhh,
                  const float* __restrict__ Wl,   const float* __restrict__ bl,
                  float* __restrict__ out, int T)
{
    const int b     = blockIdx.x;
    const int tid   = threadIdx.x;
    const int layer = tid >> 8;        // 0..2, wave-uniform (4 waves/section)
    const int sub   = tid & 255;
    const int unit  = sub >> 2;        // 0..63 (valid < 51)
    const int gt    = sub & 3;         // 0=i 1=f 2=g 3=o
    const int lane  = tid & 63;

    __shared__ __align__(16) float    xbuf[2048];
    __shared__ __align__(16) _Float16 hb[2][3][64];   // dbuf h rows, 128 B each
    __shared__ __align__(16) float    obuf[128];      // output ring (2 x 64)

    for (int i = tid; i < T; i += BLK) xbuf[i] = x[(size_t)b * T + i];
    if (tid < 192) ((float*)hb)[tid] = 0.f;           // zero both h buffers

    // ---------------- role setup ----------------
    const bool role_out = (tid == OUT_TID);
    const bool is_gate  = (unit < HID);
    const bool is_cell  = is_gate && (gt == 0);

    const float* rowA = nullptr;
    const float* rowB = nullptr;
    float wx = 0.f, bias = 0.f;
    const int selA = (layer == 0) ? 0 : layer - 1;    // section-uniform
    const int selB = layer;
    int t_off = layer;
    if (is_gate) {
        const int r = gt * HID + unit;                // PyTorch gate-row index
        if (layer == 0) {
            wx   = Wih1[r];
            bias = bih1[r] + bhh1[r];
            rowA = Whh1 + (size_t)r * 51;             // vs h0 (selA=0)
        } else {
            const int gr = (layer - 1) * 204 + r;
            bias = bih[gr] + bhh[gr];
            rowA = Wih + (size_t)gr * 51;             // vs h_{layer-1}
            rowB = Whh + (size_t)gr * 51;             // vs h_layer
        }
    } else if (role_out) {
        bias = bl[0];
        rowB = Wl;                                    // out = bl + Wl.h2 (selB=2)
        t_off = 3;
    }

    half2_t wA[26], wB[26];
    #pragma unroll
    for (int j = 0; j < 26; ++j) {
        wA[j] = half2_t{(_Float16)0.f, (_Float16)0.f};
        wB[j] = half2_t{(_Float16)0.f, (_Float16)0.f};
    }
    if (rowA) {
        #pragma unroll
        for (int j = 0; j < 25; ++j)
            wA[j] = half2_t{(_Float16)rowA[2*j], (_Float16)rowA[2*j+1]};
        wA[25] = half2_t{(_Float16)rowA[50], (_Float16)0.f};
    }
    if (rowB) {
        #pragma unroll
        for (int j = 0; j < 25; ++j)
            wB[j] = half2_t{(_Float16)rowB[2*j], (_Float16)rowB[2*j+1]};
        wB[25] = half2_t{(_Float16)rowB[50], (_Float16)0.f};
    }

    float c_state = 0.f;
    __syncthreads();

    const int TICKS = T + 4;                          // +4 so the last flush runs
    for (int tau = 0; tau < TICKS; ++tau) {
        const int par = tau & 1;
        const int  t    = tau - t_off;                // per-lane (out lane differs)
        const bool pred = (unsigned)t < (unsigned)T;

        // ---- one ds_read_b32 per lane: own h pair (2-way bank alias = free) ----
        const int psel = (lane < 32) ? selA : selB;
        const int hpx  = *(const int*)((const char*)(&hb[par][0][0])
                                       + psel * 128 + (lane & 31) * 4);

        // ---- dots via readlane broadcast (VALU pipe, not LDS pipe) ----
        float acc0 = bias, acc1 = 0.f, acc2 = 0.f, acc3 = 0.f;
        if (layer == 0) {                             // wave-uniform branch
            acc0 = fmaf(wx, xbuf[pred ? t : 0], bias);
            #pragma unroll
            for (int j = 0; j < 26; ++j) {
                const half2_t a = h2bits(__builtin_amdgcn_readlane(hpx, j));
                if (j & 1) acc1 = __builtin_amdgcn_fdot2(wA[j], a, acc1, false);
                else       acc0 = __builtin_amdgcn_fdot2(wA[j], a, acc0, false);
            }
        } else {
            #pragma unroll
            for (int j = 0; j < 26; ++j) {
                const half2_t a = h2bits(__builtin_amdgcn_readlane(hpx, j));
                const half2_t v = h2bits(__builtin_amdgcn_readlane(hpx, 32 + j));
                if (j & 1) { acc1 = __builtin_amdgcn_fdot2(wA[j], a, acc1, false);
                             acc3 = __builtin_amdgcn_fdot2(wB[j], v, acc3, false); }
                else       { acc0 = __builtin_amdgcn_fdot2(wA[j], a, acc0, false);
                             acc2 = __builtin_amdgcn_fdot2(wB[j], v, acc2, false); }
            }
        }
        const float acc = (acc0 + acc1) + (acc2 + acc3);

        // ---- quad gather: lane 4u+0 collects i,f,g,o ----
        const float fpre = __int_as_float(__builtin_amdgcn_ds_swizzle(__float_as_int(acc),  0x041F));
        const float gpre = __int_as_float(__builtin_amdgcn_ds_swizzle(__float_as_int(acc),  0x081F));
        const float opre = __int_as_float(__builtin_amdgcn_ds_swizzle(__float_as_int(fpre), 0x081F));

        if (pred) {
            if (is_cell) {
                const float si = fsig(acc);
                const float sf = fsig(fpre);
                const float tg = ftanh(gpre);
                const float so = fsig(opre);
                const float c  = fmaf(sf, c_state, si * tg);
                c_state = c;
                hb[par ^ 1][layer][unit] = (_Float16)(so * ftanh(c));
            } else if (role_out) {
                obuf[t & 127] = acc;                  // t = tau-3
            }
        }
        // ---- coalesced flush: slots read were written before last barrier ----
        if ((tid >> 6) == 3 && (tau & 63) == 3 && tau >= 67) {
            const int t0 = tau - 67;                  // multiple of 64
            out[(size_t)b * T + t0 + lane] = obuf[(t0 & 64) + lane];
        }
        __syncthreads();
    }
}

extern "C" void kernel_launch(void* const* d_in, const int* in_sizes, int n_in,
                              void* d_out, int out_size, void* d_ws, size_t ws_size,
                              hipStream_t stream) {
    const float* x    = (const float*)d_in[0];
    const float* Wih1 = (const float*)d_in[1];
    const float* Whh1 = (const float*)d_in[2];
    const float* bih1 = (const float*)d_in[3];
    const float* bhh1 = (const float*)d_in[4];
    const float* Wih  = (const float*)d_in[5];
    const float* Whh  = (const float*)d_in[6];
    const float* bih  = (const float*)d_in[7];
    const float* bhh  = (const float*)d_in[8];
    const float* Wl   = (const float*)d_in[9];
    const float* bl   = (const float*)d_in[10];
    float* out = (float*)d_out;

    const int T = in_sizes[0] / BATCH;   // 2048 (flush assumes T % 64 == 0)
    lstm3_kernel<<<BATCH, BLK, 0, stream>>>(x, Wih1, Whh1, bih1, bhh1,
                                            Wih, Whh, bih, bhh, Wl, bl, out, T);
}

// Round 9
// 1631.093 us; speedup vs baseline: 1.2134x; 1.2134x over previous
//
#include <hip/hip_runtime.h>
#include <cmath>

#define HID 51
#define BATCH 256
#define BLK 1024     // 16 waves

typedef _Float16 half2_t __attribute__((ext_vector_type(2)));

// One block per batch element (grid = 256 = #CUs -> exactly 1 block/CU).
// amdgpu_waves_per_eu(4,4) pins the allocator to 128 arch VGPRs/wave so the
// 26 packed-fp16 weight regs stay ARCH-resident (r1-r8: default occupancy
// heuristic AGPR-spilled them -> ~150 extra copies/tick, VGPR_Count 36-48).
// Roles (each a 51-pair fp16 dot vs one h row, t = tau - t_off):
//   0: layer0  bias+wx*x[t] + Whh1 row . h0   (t_off 0)
//   1: layer1  Wih row . h0  (A, carries bias) (t_off 1)
//   2: layer1  Whh row . h1  (B)               (t_off 1)
//   3: layer2  Wih row . h1  (A, carries bias) (t_off 2)
//   4: layer2  Whh row . h2  (B)               (t_off 2)
//   5: output  Wl . h2 + bl                    (t_off 3)
// Waves 0..14: role = wave/3 (role-uniform), gates (wave%3)*64+lane = 0..191.
//   h broadcast: each lane ds_read_b32 ONE h pair, then 26 x {readlane->sgpr,
//   v_dot2_f32_f16}. Wave 15: gates 192..203 of all roles (lanes 0..59, 12
//   each) + output (lane 60) via per-lane float4-from-LDS path.
// Phase A writes gate partials to gP; barrier; phase B (tid<153) combines
// A+B, cell update (c in reg), h -> hc as fp16; output ring obuf flushed
// 64-wide by wave 3 every 64 ticks; barrier.

__device__ __forceinline__ float fsig(float v) {
    return __builtin_amdgcn_rcpf(1.f + __expf(-v));
}
__device__ __forceinline__ float ftanh(float v) {
    const float e = __expf(2.f * v);                 // inf-safe
    return fmaf(-2.f, __builtin_amdgcn_rcpf(e + 1.f), 1.f);
}
__device__ __forceinline__ half2_t h2bits(int b) {
    union { int i; half2_t h; } u; u.i = b; return u.h;
}

__attribute__((amdgpu_waves_per_eu(4, 4)))
__global__ __launch_bounds__(BLK)
void lstm3_kernel(const float* __restrict__ x,
                  const float* __restrict__ Wih1, const float* __restrict__ Whh1,
                  const float* __restrict__ bih1, const float* __restrict__ bhh1,
                  const float* __restrict__ Wih,  const float* __restrict__ Whh,
                  const float* __restrict__ bih,  const float* __restrict__ bhh,
                  const float* __restrict__ Wl,   const float* __restrict__ bl,
                  float* __restrict__ out, int T)
{
    const int b    = blockIdx.x;
    const int tid  = threadIdx.x;
    const int wave = tid >> 6;
    const int lane = tid & 63;

    __shared__ __align__(16) float xbuf[2048];
    __shared__ __align__(16) int   hc[3][32];     // h rows as 26 half2 + pad (128 B apart)
    __shared__ __align__(16) float gP[5][208];    // gate (partial) pre-acts
    __shared__ __align__(16) float obuf[128];     // output ring (2 x 64)

    for (int i = tid; i < T; i += BLK) xbuf[i] = x[(size_t)b * T + i];
    if (tid < 96) ((int*)hc)[tid] = 0;            // h = 0 (both halves of all pairs)

    // ---------------- role assignment ----------------
    int role = -1, g = 0;
    if (wave < 15)       { role = wave / 3; g = (wave % 3) * 64 + lane; }
    else if (lane < 60)  { role = lane / 12; g = 192 + lane % 12; }
    else if (lane == 60) { role = 5; }

    const float* rowp = nullptr;
    float wx = 0.f, bias = 0.f;
    int srcrow = 0, t_off = 1 << 20;
    if (role == 0) {
        wx   = Wih1[g];
        bias = bih1[g] + bhh1[g];
        rowp = Whh1 + (size_t)g * 51;
        srcrow = 0; t_off = 0;
    } else if (role == 1) {
        bias = bih[g] + bhh[g];
        rowp = Wih + (size_t)g * 51;
        srcrow = 0; t_off = 1;
    } else if (role == 2) {
        rowp = Whh + (size_t)g * 51;
        srcrow = 1; t_off = 1;
    } else if (role == 3) {
        bias = bih[204 + g] + bhh[204 + g];
        rowp = Wih + (size_t)(204 + g) * 51;
        srcrow = 1; t_off = 2;
    } else if (role == 4) {
        rowp = Whh + (size_t)(204 + g) * 51;
        srcrow = 2; t_off = 2;
    } else if (role == 5) {
        bias = bl[0];
        rowp = Wl;
        srcrow = 2; t_off = 3;
    }

    half2_t w2[26];
    #pragma unroll
    for (int j = 0; j < 26; ++j) w2[j] = half2_t{(_Float16)0.f, (_Float16)0.f};
    if (rowp) {
        #pragma unroll
        for (int j = 0; j < 25; ++j)
            w2[j] = half2_t{(_Float16)rowp[2*j], (_Float16)rowp[2*j+1]};
        w2[25] = half2_t{(_Float16)rowp[50], (_Float16)0.f};
    }

    float c_state = 0.f;
    __syncthreads();

    const int TICKS = T + 4;                      // +4 so the last flush runs
    for (int tau = 0; tau < TICKS; ++tau) {
        // ---------------- phase A: gate (partial) dots ----------------
        if (wave < 15) {                          // role-uniform readlane path
            const int  t    = tau - t_off;        // wave-uniform
            const bool pred = (unsigned)t < (unsigned)T;
            const int hpx = ((const int*)hc)[srcrow * 32 + (lane & 31)];
            float acc0 = bias, acc1 = 0.f;
            if (role == 0) acc0 = fmaf(wx, xbuf[pred ? t : 0], bias);
            #pragma unroll
            for (int j = 0; j < 26; ++j) {
                const half2_t hj = h2bits(__builtin_amdgcn_readlane(hpx, j));
                if (j & 1) acc1 = __builtin_amdgcn_fdot2(w2[j], hj, acc1, false);
                else       acc0 = __builtin_amdgcn_fdot2(w2[j], hj, acc0, false);
            }
            if (pred) gP[role][g] = acc0 + acc1;
        } else if (role >= 0) {                   // wave 15: per-lane float path
            const int  t    = tau - t_off;        // per-lane
            const bool pred = (unsigned)t < (unsigned)T;
            float4 hv[7];
            const float4* hp = (const float4*)((const char*)hc + srcrow * 128);
            #pragma unroll
            for (int k = 0; k < 7; ++k) hv[k] = hp[k];
            const half2_t* hh = (const half2_t*)hv;
            float acc0 = bias, acc1 = 0.f;
            if (role == 0) acc0 = fmaf(wx, xbuf[pred ? t : 0], bias);
            #pragma unroll
            for (int j = 0; j < 26; ++j) {
                if (j & 1) acc1 = __builtin_amdgcn_fdot2(w2[j], hh[j], acc1, false);
                else       acc0 = __builtin_amdgcn_fdot2(w2[j], hh[j], acc0, false);
            }
            if (pred) {
                if (role < 5) gP[role][g] = acc0 + acc1;
                else          obuf[t & 127] = acc0 + acc1;
            }
        }
        __syncthreads();
        // ---------------- phase B: cell updates ----------------
        if (tid < 3 * HID) {
            const int cl = tid / HID, cu = tid - cl * HID;
            const int t = tau - cl;
            if ((unsigned)t < (unsigned)T) {
                float gi, gf, gg, go;
                if (cl == 0) {
                    gi = gP[0][cu];           gf = gP[0][HID + cu];
                    gg = gP[0][2*HID + cu];   go = gP[0][3*HID + cu];
                } else {
                    const int a = 2 * cl - 1;             // 1 or 3
                    gi = gP[a][cu]         + gP[a+1][cu];
                    gf = gP[a][HID + cu]   + gP[a+1][HID + cu];
                    gg = gP[a][2*HID + cu] + gP[a+1][2*HID + cu];
                    go = gP[a][3*HID + cu] + gP[a+1][3*HID + cu];
                }
                const float si = fsig(gi);
                const float sf = fsig(gf);
                const float tg = ftanh(gg);
                const float so = fsig(go);
                const float c  = fmaf(sf, c_state, si * tg);
                c_state = c;
                ((_Float16*)hc)[cl * 64 + cu] = (_Float16)(so * ftanh(c));
            }
        } else if (wave == 3 && (tau & 63) == 3 && tau >= 67) {
            // coalesced flush: all slots written before the last barrier
            const int t0 = tau - 67;                      // multiple of 64
            out[(size_t)b * T + t0 + lane] = obuf[(t0 & 64) + lane];
        }
        __syncthreads();
    }
}

extern "C" void kernel_launch(void* const* d_in, const int* in_sizes, int n_in,
                              void* d_out, int out_size, void* d_ws, size_t ws_size,
                              hipStream_t stream) {
    const float* x    = (const float*)d_in[0];
    const float* Wih1 = (const float*)d_in[1];
    const float* Whh1 = (const float*)d_in[2];
    const float* bih1 = (const float*)d_in[3];
    const float* bhh1 = (const float*)d_in[4];
    const float* Wih  = (const float*)d_in[5];
    const float* Whh  = (const float*)d_in[6];
    const float* bih  = (const float*)d_in[7];
    const float* bhh  = (const float*)d_in[8];
    const float* Wl   = (const float*)d_in[9];
    const float* bl   = (const float*)d_in[10];
    float* out = (float*)d_out;

    const int T = in_sizes[0] / BATCH;   // 2048 (flush assumes T % 64 == 0)
    lstm3_kernel<<<BATCH, BLK, 0, stream>>>(x, Wih1, Whh1, bih1, bhh1,
                                            Wih, Whh, bih, bhh, Wl, bl, out, T);
}